// Round 6
// baseline (212.238 us; speedup 1.0000x reference)
//
#include <hip/hip_runtime.h>

// Path signature M=4, d=10, L=256, B=2048.
// Thread owns (batch b, pair (i,j), k-half h): s1,s2, s3[5], s4[5][10].
// h is WAVE-UNIFORM (h = wave_id & 1): k-half selection is an s_cbranch into
// two template<K0> copies — no divergence, no runtime register indexing.
//
// ROUND-6 FIX: amdgpu_waves_per_eu(3,3). launch_bounds(.,3) only sets the MIN;
// the scheduler targeted ~10 waves/EU, capped arch VGPRs at 48, and spilled the
// ~85-float accumulator state to AGPRs (VGPR_Count=48 with no scratch traffic;
// ~130 VALU insts/step issued vs ~70 useful = accvgpr_read/write bloat).
// Pinning waves/EU to exactly 3 gives a 170-reg arch budget -> no AGPR spill.

#define D      10
#define LPATH  256
#define NSTEP  255
#define SIGTOT 11110
#define TB     256
#define SLOTS  3
#define SLOTF  (NSTEP * D)   // 2550 floats of increments per batch

template<int K0>
__device__ __forceinline__ void run_steps(const float* __restrict__ vrow,
                                          int i, int j,
                                          float& s1, float& s2,
                                          float (&s3)[5], float (&s4)[50]) {
    #pragma unroll 1
    for (int t = 0; t < NSTEP; ++t) {
        const float* row = vrow + t * D;
        float v[D];
        #pragma unroll
        for (int u = 0; u < 5; ++u)
            *(float2*)(v + 2 * u) = *(const float2*)(row + 2 * u);
        const float vi = row[i];            // LDS scalar read (broadcast-ish)
        const float vj = row[j];
        const float b_ = vj * (vi * (1.f/24.f) + s1 * (1.f/6.f)) + s2 * 0.5f;
        const float a_ = vj * (vi * (1.f/6.f)  + s1 * 0.5f)      + s2;
        s2 += vj * fmaf(vi, 0.5f, s1);      // old s1
        s1 += vi;
        float c[5];
        #pragma unroll
        for (int k = 0; k < 5; ++k) {
            const float vk = v[K0 + k];     // compile-time index
            c[k] = fmaf(b_, vk, s3[k]);     // old s3
            s3[k] = fmaf(a_, vk, s3[k]);
        }
        #pragma unroll
        for (int k = 0; k < 5; ++k) {
            #pragma unroll
            for (int l = 0; l < D; ++l)
                s4[k * 10 + l] = fmaf(c[k], v[l], s4[k * 10 + l]);
        }
    }
}

__attribute__((amdgpu_waves_per_eu(3, 3)))
__global__ __launch_bounds__(TB)
void sig_kernel(const float* __restrict__ x, float* __restrict__ out, int B) {
    __shared__ float vlds[SLOTS * SLOTF];   // 30600 B
    const int tid = threadIdx.x;
    const int blk = blockIdx.x;
    const int q0  = blk * (TB / 2);          // first pair index of this block
    const int b0  = q0 / 100;                // first batch touched
    const int bL  = (q0 + TB / 2 - 1) / 100; // last batch touched
    const int nslot = bL - b0 + 1;           // 2 or 3

    // stage increments v[t][dim] for the touched batches (coalesced)
    for (int e = tid; e < nslot * SLOTF; e += TB) {
        const int s  = e / SLOTF;
        const int r  = e - s * SLOTF;
        const int bb = b0 + s;
        float v = 0.f;
        if (bb < B) {
            const float* bx = x + (size_t)bb * (LPATH * D);
            v = bx[r + D] - bx[r];
        }
        vlds[e] = v;
    }
    __syncthreads();

    // wave-uniform half assignment: global wave w -> h = w&1; lane carries pair
    const int wg   = blk * (TB / 64) + (tid >> 6);   // global wave id
    const int lane = tid & 63;
    const int h    = wg & 1;                          // wave-uniform
    const int q    = (wg >> 1) * 64 + lane;           // pair index
    const int b    = q / 100;
    const int p    = q - b * 100;
    const int i    = p / 10;
    const int j    = p - i * 10;
    const float* vrow = vlds + (b - b0) * SLOTF;

    float s1 = 0.f, s2 = 0.f;
    float s3[5], s4[50];
    #pragma unroll
    for (int k = 0; k < 5; ++k) s3[k] = 0.f;
    #pragma unroll
    for (int k = 0; k < 50; ++k) s4[k] = 0.f;

    if (h == 0) run_steps<0>(vrow, i, j, s1, s2, s3, s4);
    else        run_steps<5>(vrow, i, j, s1, s2, s3, s4);

    // epilogue: [S1(10) | S2(100) | S3(1000) | S4(10000)] per batch
    const size_t ob = (size_t)b * SIGTOT;
    const int K0 = 5 * h;
    if (h == 0) {
        if (j == 0) out[ob + i] = s1;
        out[ob + 10 + p] = s2;
    }
    float* o3 = out + ob + 110 + (size_t)p * 10 + K0;
    #pragma unroll
    for (int k = 0; k < 5; ++k) o3[k] = s3[k];
    float* o4 = out + ob + 1110 + (size_t)p * 100 + (size_t)K0 * 10;
    #pragma unroll
    for (int k = 0; k < 5; ++k) {
        #pragma unroll
        for (int lp = 0; lp < 5; ++lp) {
            *(float2*)(o4 + k * 10 + 2 * lp) =
                make_float2(s4[k * 10 + 2 * lp], s4[k * 10 + 2 * lp + 1]);
        }
    }
}

extern "C" void kernel_launch(void* const* d_in, const int* in_sizes, int n_in,
                              void* d_out, int out_size, void* d_ws, size_t ws_size,
                              hipStream_t stream) {
    const float* x = (const float*)d_in[0];
    float* out = (float*)d_out;
    const int B = in_sizes[0] / (LPATH * D);        // 2048
    const int nthreads = B * 100 * 2;               // 409600
    const int nblocks = nthreads / TB;              // 1600
    sig_kernel<<<nblocks, TB, 0, stream>>>(x, out, B);
}